// Round 1
// baseline (1159.188 us; speedup 1.0000x reference)
//
#include <hip/hip_runtime.h>

typedef __bf16 bf16x8 __attribute__((ext_vector_type(8)));
typedef float f32x4 __attribute__((ext_vector_type(4)));
typedef unsigned short u16;
typedef unsigned int u32;

#define MFMA(a, b, c) __builtin_amdgcn_mfma_f32_16x16x32_bf16((a), (b), (c), 0, 0, 0)

// B=2, L=2048, D=1024, H=16, DH=64
// d_out: out [B,L,D] (4,194,304 f32) then attn [B,H,L,L] (134,217,728 f32)

__device__ __forceinline__ u16 f2bf(float f) {
  u32 u = __float_as_uint(f);
  return (u16)((u + 0x7fffu + ((u >> 16) & 1u)) >> 16);
}

// ---------------- fp32 -> bf16 convert (vectorized) ----------------
__global__ __launch_bounds__(256) void cvt_bf16(const float4* __restrict__ x,
                                                uint2* __restrict__ y, int n4) {
  int i = blockIdx.x * 256 + threadIdx.x;
  if (i >= n4) return;
  float4 v = x[i];
  uint2 o;
  o.x = (u32)f2bf(v.x) | ((u32)f2bf(v.y) << 16);
  o.y = (u32)f2bf(v.z) | ((u32)f2bf(v.w) << 16);
  y[i] = o;
}

// ---------------- conv weight transpose [H,D,3] -> [H,3,D] ----------------
__global__ __launch_bounds__(256) void prep_cw(const float* __restrict__ cw,
                                               float* __restrict__ cwT) {
  int i = blockIdx.x * 256 + threadIdx.x;
  if (i >= 16 * 3 * 1024) return;
  int h = i / 3072;
  int j = (i - h * 3072) >> 10;
  int d = i & 1023;
  cwT[i] = cw[(h * 1024 + d) * 3 + j];
}

// ---------------- saliency conv: sal[b,h,l] = sum_{j,d} src[b,l+j-1,d]*w[h,d,j] + cb[h]
__global__ __launch_bounds__(256) void conv_sal_k(const float* __restrict__ src,
                                                  const float* __restrict__ cwT,
                                                  const float* __restrict__ cb,
                                                  float* __restrict__ sal) {
  const int t = threadIdx.x;
  const int h = t & 15, li = t >> 4;
  const int b = blockIdx.y;
  const int l = blockIdx.x * 16 + li;
  float acc = cb[h];
#pragma unroll
  for (int j = 0; j < 3; j++) {
    int ls = l + j - 1;
    if (ls < 0 || ls >= 2048) continue;
    const float4* sp = (const float4*)(src + ((size_t)b * 2048 + ls) * 1024);
    const float4* wp = (const float4*)(cwT + (h * 3 + j) * 1024);
    float s = 0.f;
    for (int d = 0; d < 256; d++) {
      float4 a = sp[d], w = wp[d];
      s += a.x * w.x + a.y * w.y + a.z * w.z + a.w * w.w;
    }
    acc += s;
  }
  sal[(b * 16 + h) * 2048 + l] = acc;
}

// ---------------- fused QKV projection GEMM ----------------
// Y = X @ W^T + b ; X [4096,1024] bf16, W [1024,1024] bf16 (row-major, torch Linear)
// seg 0->Q [B,H,L,64], seg 1->K [B,H,L,64], seg 2->V transposed [B,H,64,L]
__global__ __launch_bounds__(256) void qkv_gemm(
    const u16* __restrict__ Xb, const u16* __restrict__ Wqb, const u16* __restrict__ Wkb,
    const u16* __restrict__ Wvb, const float* __restrict__ bq, const float* __restrict__ bk,
    const float* __restrict__ bv, u16* __restrict__ Qb, u16* __restrict__ Kb,
    u16* __restrict__ Vt) {
  const int seg = blockIdx.x >> 3;
  const u16* __restrict__ W = (seg == 0) ? Wqb : (seg == 1) ? Wkb : Wvb;
  const float* __restrict__ bias = (seg == 0) ? bq : (seg == 1) ? bk : bv;
  const int lane = threadIdx.x & 63, wid = threadIdx.x >> 6;
  const int cl = lane & 15, gp = lane >> 4;
  const int m0 = blockIdx.y * 128 + (wid >> 1) * 64;
  const int n0 = (blockIdx.x & 7) * 128 + (wid & 1) * 64;
  const u16* Xp = Xb + (size_t)(m0 + cl) * 1024 + gp * 8;
  const u16* Wp = W + (size_t)(n0 + cl) * 1024 + gp * 8;
  f32x4 acc[4][4] = {};
  for (int k = 0; k < 1024; k += 32) {
    bf16x8 a[4], b[4];
#pragma unroll
    for (int t = 0; t < 4; t++) {
      a[t] = *(const bf16x8*)(Xp + t * 16 * 1024 + k);
      b[t] = *(const bf16x8*)(Wp + t * 16 * 1024 + k);
    }
#pragma unroll
    for (int tm = 0; tm < 4; tm++)
#pragma unroll
      for (int tn = 0; tn < 4; tn++) acc[tm][tn] = MFMA(a[tm], b[tn], acc[tm][tn]);
  }
#pragma unroll
  for (int tn = 0; tn < 4; tn++) {
    int col = n0 + tn * 16 + cl;
    float bv_ = bias[col];
    int hh = col >> 6, dh = col & 63;
#pragma unroll
    for (int tm = 0; tm < 4; tm++) {
#pragma unroll
      for (int r = 0; r < 4; r++) {
        int row = m0 + tm * 16 + gp * 4 + r;
        u16 hv = f2bf(acc[tm][tn][r] + bv_);
        int bb = row >> 11, l = row & 2047;
        if (seg == 0)
          Qb[(((size_t)(bb * 16 + hh) * 2048 + l) << 6) + dh] = hv;
        else if (seg == 1)
          Kb[(((size_t)(bb * 16 + hh) * 2048 + l) << 6) + dh] = hv;
        else
          Vt[((size_t)(bb * 16 + hh) * 64 + dh) * 2048 + l] = hv;
      }
    }
  }
}

// ---------------- out projection GEMM: out = O @ Wo^T + bo (fp32 out) ----------------
__global__ __launch_bounds__(256) void out_gemm(const u16* __restrict__ Xb,
                                                const u16* __restrict__ W,
                                                const float* __restrict__ bias,
                                                float* __restrict__ Y) {
  const int lane = threadIdx.x & 63, wid = threadIdx.x >> 6;
  const int cl = lane & 15, gp = lane >> 4;
  const int m0 = blockIdx.y * 128 + (wid >> 1) * 64;
  const int n0 = blockIdx.x * 128 + (wid & 1) * 64;
  const u16* Xp = Xb + (size_t)(m0 + cl) * 1024 + gp * 8;
  const u16* Wp = W + (size_t)(n0 + cl) * 1024 + gp * 8;
  f32x4 acc[4][4] = {};
  for (int k = 0; k < 1024; k += 32) {
    bf16x8 a[4], b[4];
#pragma unroll
    for (int t = 0; t < 4; t++) {
      a[t] = *(const bf16x8*)(Xp + t * 16 * 1024 + k);
      b[t] = *(const bf16x8*)(Wp + t * 16 * 1024 + k);
    }
#pragma unroll
    for (int tm = 0; tm < 4; tm++)
#pragma unroll
      for (int tn = 0; tn < 4; tn++) acc[tm][tn] = MFMA(a[tm], b[tn], acc[tm][tn]);
  }
#pragma unroll
  for (int tn = 0; tn < 4; tn++) {
    int col = n0 + tn * 16 + cl;
    float bv_ = bias[col];
#pragma unroll
    for (int tm = 0; tm < 4; tm++)
#pragma unroll
      for (int r = 0; r < 4; r++) {
        int row = m0 + tm * 16 + gp * 4 + r;
        Y[(size_t)row * 1024 + col] = acc[tm][tn][r] + bv_;
      }
  }
}

// ---------------- flash pass 1: per-row m, 1/l, and O = softmax(S) @ V ----------------
// wave handles 16 queries; block = 64 queries of one (b,h)
__global__ __launch_bounds__(256) void flash1(const u16* __restrict__ Qb,
                                              const u16* __restrict__ Kb,
                                              const u16* __restrict__ Vt,
                                              const float* __restrict__ sal,
                                              float* __restrict__ mrow,
                                              float* __restrict__ invl,
                                              u16* __restrict__ Ob) {
  __shared__ __align__(16) u16 pbuf[4][16][72];  // per-wave 16x64 P tile, padded stride 72
  const int bh = blockIdx.x;
  const int b = bh >> 4, h = bh & 15;
  const int lane = threadIdx.x & 63, wid = threadIdx.x >> 6;
  const int cl = lane & 15, gp = lane >> 4;
  const int q0 = blockIdx.y * 64 + wid * 16;
  const u16* Qh = Qb + (size_t)bh * 2048 * 64;
  const u16* Kh = Kb + (size_t)bh * 2048 * 64;
  const u16* Vh = Vt + (size_t)bh * 64 * 2048;
  const float* salh = sal + bh * 2048;
  bf16x8 aQ0 = *(const bf16x8*)(Qh + (size_t)(q0 + cl) * 64 + gp * 8);
  bf16x8 aQ1 = *(const bf16x8*)(Qh + (size_t)(q0 + cl) * 64 + 32 + gp * 8);
  f32x4 oacc[4] = {};
  float m[4], l[4];
#pragma unroll
  for (int r = 0; r < 4; r++) { m[r] = -1e30f; l[r] = 0.f; }
  u16* pw = &pbuf[wid][0][0];
  for (int kb = 0; kb < 2048; kb += 64) {
    f32x4 st[4];
#pragma unroll
    for (int tn = 0; tn < 4; tn++) {
      const u16* kp = Kh + (size_t)(kb + tn * 16 + cl) * 64 + gp * 8;
      f32x4 s = {};
      s = MFMA(aQ0, *(const bf16x8*)kp, s);
      s = MFMA(aQ1, *(const bf16x8*)(kp + 32), s);
      st[tn] = s;
    }
#pragma unroll
    for (int tn = 0; tn < 4; tn++) {
      float sv = salh[kb + tn * 16 + cl];
#pragma unroll
      for (int r = 0; r < 4; r++) st[tn][r] = st[tn][r] * 0.125f + sv;
    }
    float mn[4], alpha[4];
#pragma unroll
    for (int r = 0; r < 4; r++) {
      float v = fmaxf(fmaxf(st[0][r], st[1][r]), fmaxf(st[2][r], st[3][r]));
      v = fmaxf(v, __shfl_xor(v, 1));
      v = fmaxf(v, __shfl_xor(v, 2));
      v = fmaxf(v, __shfl_xor(v, 4));
      v = fmaxf(v, __shfl_xor(v, 8));
      mn[r] = fmaxf(m[r], v);
      alpha[r] = __expf(m[r] - mn[r]);
      m[r] = mn[r];
    }
#pragma unroll
    for (int r = 0; r < 4; r++) {
      float s0 = 0.f;
#pragma unroll
      for (int tn = 0; tn < 4; tn++) {
        float p = __expf(st[tn][r] - mn[r]);
        st[tn][r] = p;
        s0 += p;
      }
      s0 += __shfl_xor(s0, 1);
      s0 += __shfl_xor(s0, 2);
      s0 += __shfl_xor(s0, 4);
      s0 += __shfl_xor(s0, 8);
      l[r] = l[r] * alpha[r] + s0;
#pragma unroll
      for (int tn = 0; tn < 4; tn++) oacc[tn][r] *= alpha[r];
    }
    // C-layout -> A-layout via per-wave LDS tile (barriers defeat TBAA reordering)
#pragma unroll
    for (int tn = 0; tn < 4; tn++)
#pragma unroll
      for (int r = 0; r < 4; r++) pw[(gp * 4 + r) * 72 + tn * 16 + cl] = f2bf(st[tn][r]);
    __syncthreads();
    bf16x8 aP0 = *(const bf16x8*)(pw + cl * 72 + gp * 8);
    bf16x8 aP1 = *(const bf16x8*)(pw + cl * 72 + 32 + gp * 8);
#pragma unroll
    for (int tn = 0; tn < 4; tn++) {
      const u16* vp = Vh + (size_t)(tn * 16 + cl) * 2048 + kb + gp * 8;
      oacc[tn] = MFMA(aP0, *(const bf16x8*)vp, oacc[tn]);
      oacc[tn] = MFMA(aP1, *(const bf16x8*)(vp + 32), oacc[tn]);
    }
    __syncthreads();
  }
  float inv[4];
#pragma unroll
  for (int r = 0; r < 4; r++) inv[r] = 1.0f / l[r];
#pragma unroll
  for (int tn = 0; tn < 4; tn++) {
    int d = h * 64 + tn * 16 + cl;
#pragma unroll
    for (int r = 0; r < 4; r++) {
      int q = q0 + gp * 4 + r;
      Ob[((size_t)(b * 2048 + q)) * 1024 + d] = f2bf(oacc[tn][r] * inv[r]);
    }
  }
  if (cl == 0) {
#pragma unroll
    for (int r = 0; r < 4; r++) {
      int q = q0 + gp * 4 + r;
      mrow[bh * 2048 + q] = m[r];
      invl[bh * 2048 + q] = inv[r];
    }
  }
}

// ---------------- flash pass 2: recompute S, write normalized attn (fp32) ----------------
__global__ __launch_bounds__(256) void attn_write(const u16* __restrict__ Qb,
                                                  const u16* __restrict__ Kb,
                                                  const float* __restrict__ sal,
                                                  const float* __restrict__ mrow,
                                                  const float* __restrict__ invl,
                                                  float* __restrict__ attn) {
  const int bh = blockIdx.x;
  const int lane = threadIdx.x & 63, wid = threadIdx.x >> 6;
  const int cl = lane & 15, gp = lane >> 4;
  const int q0 = blockIdx.y * 64 + wid * 16;
  const u16* Qh = Qb + (size_t)bh * 2048 * 64;
  const u16* Kh = Kb + (size_t)bh * 2048 * 64;
  const float* salh = sal + bh * 2048;
  bf16x8 aQ0 = *(const bf16x8*)(Qh + (size_t)(q0 + cl) * 64 + gp * 8);
  bf16x8 aQ1 = *(const bf16x8*)(Qh + (size_t)(q0 + cl) * 64 + 32 + gp * 8);
  float m[4], il[4];
#pragma unroll
  for (int r = 0; r < 4; r++) {
    int q = q0 + gp * 4 + r;
    m[r] = mrow[bh * 2048 + q];
    il[r] = invl[bh * 2048 + q];
  }
  float* arow = attn + (size_t)bh * 2048 * 2048;
  for (int kb = 0; kb < 2048; kb += 64) {
    f32x4 st[4];
#pragma unroll
    for (int tn = 0; tn < 4; tn++) {
      const u16* kp = Kh + (size_t)(kb + tn * 16 + cl) * 64 + gp * 8;
      f32x4 s = {};
      s = MFMA(aQ0, *(const bf16x8*)kp, s);
      s = MFMA(aQ1, *(const bf16x8*)(kp + 32), s);
      st[tn] = s;
    }
#pragma unroll
    for (int tn = 0; tn < 4; tn++) {
      float sv = salh[kb + tn * 16 + cl];
#pragma unroll
      for (int r = 0; r < 4; r++) {
        int q = q0 + gp * 4 + r;
        float p = __expf(st[tn][r] * 0.125f + sv - m[r]) * il[r];
        arow[(size_t)q * 2048 + kb + tn * 16 + cl] = p;
      }
    }
  }
}

// ---------------- launch ----------------
extern "C" void kernel_launch(void* const* d_in, const int* in_sizes, int n_in,
                              void* d_out, int out_size, void* d_ws, size_t ws_size,
                              hipStream_t stream) {
  const float* src = (const float*)d_in[0];
  const float* Wq = (const float*)d_in[1];
  const float* bq = (const float*)d_in[2];
  const float* Wk = (const float*)d_in[3];
  const float* bk = (const float*)d_in[4];
  const float* Wv = (const float*)d_in[5];
  const float* bv = (const float*)d_in[6];
  const float* Wo = (const float*)d_in[7];
  const float* bo = (const float*)d_in[8];
  const float* cw = (const float*)d_in[9];
  const float* cb = (const float*)d_in[10];

  char* ws = (char*)d_ws;
  u16* srcb = (u16*)(ws + 0);          // 8,388,608 B
  u16* wqb = (u16*)(ws + 8388608);     // 2,097,152 B
  u16* wkb = (u16*)(ws + 10485760);
  u16* wvb = (u16*)(ws + 12582912);
  u16* wob = (u16*)(ws + 14680064);
  u16* Qb = (u16*)(ws + 16777216);     // 8,388,608 B  [B,H,L,64] bf16
  u16* Kb = (u16*)(ws + 25165824);
  u16* Vt = (u16*)(ws + 33554432);     // [B,H,64,L] bf16
  u16* Ob = (u16*)(ws + 41943040);     // [B,L,D] bf16
  float* cwT = (float*)(ws + 50331648);
  float* sal = (float*)(ws + 50528256);
  float* mrow = (float*)(ws + 50790400);
  float* invl = (float*)(ws + 51052544);  // end 51,314,688

  float* outp = (float*)d_out;
  float* attn = (float*)d_out + 4194304;

  cvt_bf16<<<4096, 256, 0, stream>>>((const float4*)src, (uint2*)srcb, 1048576);
  cvt_bf16<<<1024, 256, 0, stream>>>((const float4*)Wq, (uint2*)wqb, 262144);
  cvt_bf16<<<1024, 256, 0, stream>>>((const float4*)Wk, (uint2*)wkb, 262144);
  cvt_bf16<<<1024, 256, 0, stream>>>((const float4*)Wv, (uint2*)wvb, 262144);
  cvt_bf16<<<1024, 256, 0, stream>>>((const float4*)Wo, (uint2*)wob, 262144);
  prep_cw<<<192, 256, 0, stream>>>(cw, cwT);
  conv_sal_k<<<dim3(128, 2), 256, 0, stream>>>(src, cwT, cb, sal);
  qkv_gemm<<<dim3(24, 32), 256, 0, stream>>>(srcb, wqb, wkb, wvb, bq, bk, bv, Qb, Kb, Vt);
  flash1<<<dim3(32, 32), 256, 0, stream>>>(Qb, Kb, Vt, sal, mrow, invl, Ob);
  attn_write<<<dim3(32, 32), 256, 0, stream>>>(Qb, Kb, sal, mrow, invl, attn);
  out_gemm<<<dim3(8, 32), 256, 0, stream>>>(Ob, wob, bo, outp);
}